// Round 2
// baseline (241.245 us; speedup 1.0000x reference)
//
#include <hip/hip_runtime.h>
#include <math.h>

#define BATCH 32
#define SEQ   8192
#define HID   512
#define NC    32   // blocks per batch in pass1; each block covers 256 rows

typedef float f4 __attribute__((ext_vector_type(4)));

// Pass 1 (fused): per block of 256 rows:
//   - attn[b,s] = dot(output[b,:], context[b,s,:])  -> written raw to d_out
//   - online masked softmax partials (m, D, weighted acc over context rows)
// Wave = 64 rows; lane owns 8 consecutive H columns. 4 waves combine in LDS,
// block writes ONE partial {m, D, acc[512]}.
__global__ __launch_bounds__(256) void k_pass1(
    const float* __restrict__ outp, const float* __restrict__ ctx,
    const int* __restrict__ split, float* __restrict__ attn_out,
    float* __restrict__ pacc, float* __restrict__ pmd)
{
  const int tid = threadIdx.x, lane = tid & 63, wave = tid >> 6;
  const int b = blockIdx.x >> 5, blk = blockIdx.x & 31;
  const int sp = split[b];

  const float* ob = outp + b * HID + lane * 8;
  f4 o0 = *reinterpret_cast<const f4*>(ob);
  f4 o1 = *reinterpret_cast<const f4*>(ob + 4);

  const int s_base = blk * 256 + wave * 64;
  const float* cb = ctx + ((size_t)b * SEQ + s_base) * HID + lane * 8;
  float* ao = attn_out + (size_t)b * SEQ + s_base;

  float m = -INFINITY, d = 0.f;
  float acc[8] = {0.f,0.f,0.f,0.f,0.f,0.f,0.f,0.f};

  for (int g = 0; g < 8; ++g) {          // 8 groups of 8 rows
    const int sg = g * 8;
    f4 c0[8], c1[8];
    float a[8];
#pragma unroll
    for (int i = 0; i < 8; ++i) {
      const float* rp = cb + (size_t)(sg + i) * HID;
      c0[i] = *reinterpret_cast<const f4*>(rp);
      c1[i] = *reinterpret_cast<const f4*>(rp + 4);
      float v = 0.f;
#pragma unroll
      for (int j = 0; j < 4; ++j) v += o0[j] * c0[i][j] + o1[j] * c1[i][j];
      a[i] = v;
    }
#pragma unroll
    for (int i = 0; i < 8; ++i) {
#pragma unroll
      for (int off = 32; off >= 1; off >>= 1) a[i] += __shfl_xor(a[i], off, 64);
      if (lane == i) ao[sg + i] = a[i];   // raw (unmasked) attn output
    }
    const int s0g = s_base + sg;
    if (s0g < sp) {                       // group has at least one unmasked row
      float gm = -INFINITY;
#pragma unroll
      for (int i = 0; i < 8; ++i) {
        if (s0g + i >= sp) a[i] = -INFINITY;
        gm = fmaxf(gm, a[i]);
      }
      const float nm = fmaxf(m, gm);      // finite: row s0g is unmasked
      const float sc = __expf(m - nm);
      float w[8], ds = 0.f;
#pragma unroll
      for (int i = 0; i < 8; ++i) { w[i] = __expf(a[i] - nm); ds += w[i]; }
      d = d * sc + ds;
#pragma unroll
      for (int j = 0; j < 4; ++j) {
        float t0 = acc[j] * sc, t1 = acc[4 + j] * sc;
#pragma unroll
        for (int i = 0; i < 8; ++i) { t0 += w[i] * c0[i][j]; t1 += w[i] * c1[i][j]; }
        acc[j] = t0; acc[4 + j] = t1;
      }
      m = nm;
    }
  }

  // Block-level combine of the 4 wave partials via LDS
  __shared__ float lacc[4][HID];
  __shared__ float lmd[4][2];
  {
    f4 v0, v1;
#pragma unroll
    for (int j = 0; j < 4; ++j) { v0[j] = acc[j]; v1[j] = acc[4 + j]; }
    *reinterpret_cast<f4*>(&lacc[wave][lane * 8])     = v0;
    *reinterpret_cast<f4*>(&lacc[wave][lane * 8 + 4]) = v1;
  }
  if (lane == 0) { lmd[wave][0] = m; lmd[wave][1] = d; }
  __syncthreads();

  const float M = fmaxf(fmaxf(lmd[0][0], lmd[1][0]), fmaxf(lmd[2][0], lmd[3][0]));
  const size_t pb = (size_t)b * NC + blk;
  float* pa = pacc + pb * HID;
  if (M == -INFINITY) {                   // whole block masked out
    pa[tid * 2] = 0.f; pa[tid * 2 + 1] = 0.f;
    if (tid == 0) { pmd[pb * 2] = -INFINITY; pmd[pb * 2 + 1] = 0.f; }
  } else {
    float e[4], Dl = 0.f;
#pragma unroll
    for (int wv = 0; wv < 4; ++wv) { e[wv] = __expf(lmd[wv][0] - M); Dl += e[wv] * lmd[wv][1]; }
    float s0 = 0.f, s1 = 0.f;
#pragma unroll
    for (int wv = 0; wv < 4; ++wv) {
      s0 += e[wv] * lacc[wv][tid * 2];
      s1 += e[wv] * lacc[wv][tid * 2 + 1];
    }
    pa[tid * 2] = s0; pa[tid * 2 + 1] = s1;
    if (tid == 0) { pmd[pb * 2] = M; pmd[pb * 2 + 1] = Dl; }
  }
}

// Pass 2: per batch — merge 32 block partials -> a_mix; gather det row and
// output row; GEMV (4H -> H) with W rows + bias; tanh.
__global__ __launch_bounds__(512) void k_final(
    const float* __restrict__ outp, const float* __restrict__ ctx,
    const int* __restrict__ split, const float* __restrict__ W,
    const float* __restrict__ bias, const float* __restrict__ pacc,
    const float* __restrict__ pmd, float* __restrict__ out0)
{
  const int b = blockIdx.x, h = threadIdx.x;
  __shared__ float sm[NC], sDd[NC], swgt[NC];
  __shared__ float amix[HID], det[HID], oup[HID];

  if (h < NC) {
    sm[h]  = pmd[((size_t)b * NC + h) * 2];
    sDd[h] = pmd[((size_t)b * NC + h) * 2 + 1];
  }
  __syncthreads();
  float M = -INFINITY;
#pragma unroll
  for (int c = 0; c < NC; ++c) M = fmaxf(M, sm[c]);
  if (h < NC) swgt[h] = __expf(sm[h] - M);
  __syncthreads();
  float D = 0.f;
#pragma unroll
  for (int c = 0; c < NC; ++c) D += swgt[c] * sDd[c];
  float am = 0.f;
  for (int c = 0; c < NC; ++c) am += swgt[c] * pacc[((size_t)b * NC + c) * HID + h];
  amix[h] = am / D;
  const int sp = split[b];
  det[h] = ctx[((size_t)b * SEQ + sp) * HID + h];
  oup[h] = outp[b * HID + h];
  __syncthreads();

  float acc = bias[h];
  const float* wr = W + (size_t)h * (4 * HID);
  for (int k0 = 0; k0 < HID; k0 += 4) {
    f4 w0 = *reinterpret_cast<const f4*>(wr + k0);
    f4 w1 = *reinterpret_cast<const f4*>(wr + HID + k0);
    f4 w2 = *reinterpret_cast<const f4*>(wr + 2 * HID + k0);
    f4 w3 = *reinterpret_cast<const f4*>(wr + 3 * HID + k0);
#pragma unroll
    for (int j = 0; j < 4; ++j)
      acc += amix[k0 + j] * (w0[j] + w1[j]) + det[k0 + j] * w2[j] + oup[k0 + j] * w3[j];
  }
  out0[b * HID + h] = tanhf(acc);
}

extern "C" void kernel_launch(void* const* d_in, const int* in_sizes, int n_in,
                              void* d_out, int out_size, void* d_ws, size_t ws_size,
                              hipStream_t stream)
{
  const float* outp = (const float*)d_in[0]; // [B,1,H] f32
  const float* ctx  = (const float*)d_in[1]; // [B,S,H] f32
  const int*   spl  = (const int*)d_in[2];   // [B] int32
  const float* W    = (const float*)d_in[3]; // [H,4H] f32
  const float* bias = (const float*)d_in[4]; // [H] f32

  float* out0   = (float*)d_out;                       // B*H f32
  float* attn_o = out0 + (size_t)BATCH * HID;          // B*S f32

  float* pacc = (float*)d_ws;                          // B*NC*HID f32 (2 MB)
  float* pmd  = pacc + (size_t)BATCH * NC * HID;       // B*NC*2 f32

  k_pass1<<<BATCH * NC, 256, 0, stream>>>(outp, ctx, spl, attn_o, pacc, pmd);
  k_final<<<BATCH,      512, 0, stream>>>(outp, ctx, spl, W, bias, pacc, pmd, out0);
}

// Round 3
// 138.853 us; speedup vs baseline: 1.7374x; 1.7374x over previous
//
#include <hip/hip_runtime.h>
#include <math.h>

#define BATCH 32
#define SEQ   8192
#define HID   512
#define STRIPES 16                        // pass1 blocks per batch
#define RPB   (SEQ / STRIPES)             // 512 rows per block
#define CR    16                          // chunk rows (32 KB per chunk)
#define NCHUNK (RPB / CR)                 // 32 chunks

typedef float f4 __attribute__((ext_vector_type(4)));

__device__ __forceinline__ void gload_lds(const float* g, float* l) {
  __builtin_amdgcn_global_load_lds(
      (const __attribute__((address_space(1))) void*)g,
      (__attribute__((address_space(3))) void*)l, 16, 0, 0);
}

// Pass 1 (fused, LDS-staged): per block = 512 rows of one batch.
// Double-buffered 16-row chunks via global_load_lds; per chunk each wave
// computes 4 row-dots (butterfly), writes raw attn, and does the online
// masked-softmax update reusing the same LDS-read registers.
__global__ __launch_bounds__(256, 2) void k_pass1(
    const float* __restrict__ outp, const float* __restrict__ ctx,
    const int* __restrict__ split, float* __restrict__ attn_out,
    float* __restrict__ pacc, float* __restrict__ pmd)
{
  __shared__ float lds[2][CR][HID];       // 64 KB
  const int tid = threadIdx.x, lane = tid & 63, wave = tid >> 6;
  const int b = blockIdx.x >> 4;          // STRIPES == 16
  const int stripe = blockIdx.x & 15;
  const int sp = split[b];
  const int s_base = stripe * RPB;

  const float* ob = outp + b * HID + lane * 8;
  const f4 o0 = *(const f4*)ob;
  const f4 o1 = *(const f4*)(ob + 4);

  const float* cbase = ctx + ((size_t)b * SEQ + s_base) * HID;
  float* ao = attn_out + (size_t)b * SEQ + s_base;

  // prefetch chunk 0 -> buf 0 (each wave issues 8 x 1KB)
#pragma unroll
  for (int i = 0; i < 8; ++i) {
    const int o = (wave * 8 + i) * 256;
    gload_lds(cbase + o + lane * 4, &lds[0][0][0] + o);
  }

  float m = -INFINITY, d = 0.f;
  f4 acc0 = {0.f, 0.f, 0.f, 0.f}, acc1 = {0.f, 0.f, 0.f, 0.f};

  __syncthreads();                        // chunk 0 resident

  for (int c = 0; c < NCHUNK; ++c) {
    const int cur = c & 1;
    if (c + 1 < NCHUNK) {                 // issue next-chunk loads first
      const float* src = cbase + (size_t)(c + 1) * CR * HID;
      float* dst = &lds[cur ^ 1][0][0];
#pragma unroll
      for (int i = 0; i < 8; ++i) {
        const int o = (wave * 8 + i) * 256;
        gload_lds(src + o + lane * 4, dst + o);
      }
    }

    float a4[4];
#pragma unroll
    for (int k = 0; k < 4; ++k) {
      const int r = wave * 4 + k;
      const float* rp = &lds[cur][r][lane * 8];
      const f4 c0 = *(const f4*)rp;
      const f4 c1 = *(const f4*)(rp + 4);
      float v = o0[0]*c0[0] + o0[1]*c0[1] + o0[2]*c0[2] + o0[3]*c0[3]
              + o1[0]*c1[0] + o1[1]*c1[1] + o1[2]*c1[2] + o1[3]*c1[3];
#pragma unroll
      for (int off = 32; off >= 1; off >>= 1) v += __shfl_xor(v, off, 64);
      a4[k] = v;
      const int s = s_base + c * CR + r;  // wave-uniform branch
      if (s < sp) {
        const float nm = fmaxf(m, v);
        const float sc = __expf(m - nm);
        const float w  = __expf(v - nm);
        d = d * sc + w;
        acc0 = acc0 * sc + w * c0;
        acc1 = acc1 * sc + w * c1;
        m = nm;
      }
    }
    if (lane == 0) {
      f4 st = {a4[0], a4[1], a4[2], a4[3]};
      *(f4*)(ao + c * CR + wave * 4) = st;
    }
    __syncthreads();                      // drains prefetch; buffers safe
  }

  // merge 4 wave partials via LDS (buffers are free now)
  float* lacc = &lds[0][0][0];            // [4][HID]
  float* lmd  = &lds[1][0][0];            // [4][2]
  *(f4*)(lacc + wave * HID + lane * 8)     = acc0;
  *(f4*)(lacc + wave * HID + lane * 8 + 4) = acc1;
  if (lane == 0) { lmd[wave * 2] = m; lmd[wave * 2 + 1] = d; }
  __syncthreads();

  const float M = fmaxf(fmaxf(lmd[0], lmd[2]), fmaxf(lmd[4], lmd[6]));
  const size_t pb = (size_t)b * STRIPES + stripe;
  float* pa = pacc + pb * HID;
  if (M == -INFINITY) {
    pa[tid * 2] = 0.f; pa[tid * 2 + 1] = 0.f;
    if (tid == 0) { pmd[pb * 2] = -INFINITY; pmd[pb * 2 + 1] = 0.f; }
  } else {
    float e[4], Dl = 0.f;
#pragma unroll
    for (int wv = 0; wv < 4; ++wv) {
      const float mw = lmd[wv * 2];
      e[wv] = (mw == -INFINITY) ? 0.f : __expf(mw - M);
      Dl += e[wv] * lmd[wv * 2 + 1];
    }
    float s0 = 0.f, s1 = 0.f;
#pragma unroll
    for (int wv = 0; wv < 4; ++wv) {
      s0 += e[wv] * lacc[wv * HID + tid * 2];
      s1 += e[wv] * lacc[wv * HID + tid * 2 + 1];
    }
    pa[tid * 2] = s0; pa[tid * 2 + 1] = s1;
    if (tid == 0) { pmd[pb * 2] = M; pmd[pb * 2 + 1] = Dl; }
  }
}

// Pass 2: block (b, q) computes 64 outputs h = q*64+t.
// Merge 16 stripe partials -> a_mix; GEMV over W slice + tanh.
__global__ __launch_bounds__(64) void k_final(
    const float* __restrict__ outp, const float* __restrict__ ctx,
    const int* __restrict__ split, const float* __restrict__ W,
    const float* __restrict__ bias, const float* __restrict__ pacc,
    const float* __restrict__ pmd, float* __restrict__ out0)
{
  const int b = blockIdx.x >> 3, q = blockIdx.x & 7;
  const int t = threadIdx.x;
  __shared__ float amix[HID], det[HID], oup[HID];

  float M = -INFINITY;
#pragma unroll
  for (int c = 0; c < STRIPES; ++c) M = fmaxf(M, pmd[(b * STRIPES + c) * 2]);
  float wgt[STRIPES], D = 0.f;
#pragma unroll
  for (int c = 0; c < STRIPES; ++c) {
    const float mw = pmd[(b * STRIPES + c) * 2];
    wgt[c] = (mw == -INFINITY) ? 0.f : __expf(mw - M);
    D += wgt[c] * pmd[(b * STRIPES + c) * 2 + 1];
  }
  const float invD = 1.f / D;
  const int sp = split[b];
#pragma unroll
  for (int j = 0; j < 8; ++j) {
    const int col = t * 8 + j;
    float s = 0.f;
    for (int c = 0; c < STRIPES; ++c)
      s += wgt[c] * pacc[((size_t)(b * STRIPES + c)) * HID + col];
    amix[col] = s * invD;
    det[col] = ctx[((size_t)b * SEQ + sp) * HID + col];
    oup[col] = outp[b * HID + col];
  }
  __syncthreads();

  const int h = q * 64 + t;
  float acc = bias[h];
  const float* wr = W + (size_t)h * (4 * HID);
  for (int k0 = 0; k0 < HID; k0 += 4) {
    const f4 w0 = *(const f4*)(wr + k0);
    const f4 w1 = *(const f4*)(wr + HID + k0);
    const f4 w2 = *(const f4*)(wr + 2 * HID + k0);
    const f4 w3 = *(const f4*)(wr + 3 * HID + k0);
#pragma unroll
    for (int j = 0; j < 4; ++j)
      acc += amix[k0 + j] * (w0[j] + w1[j]) + det[k0 + j] * w2[j] + oup[k0 + j] * w3[j];
  }
  out0[b * HID + h] = tanhf(acc);
}

extern "C" void kernel_launch(void* const* d_in, const int* in_sizes, int n_in,
                              void* d_out, int out_size, void* d_ws, size_t ws_size,
                              hipStream_t stream)
{
  const float* outp = (const float*)d_in[0]; // [B,1,H] f32
  const float* ctx  = (const float*)d_in[1]; // [B,S,H] f32
  const int*   spl  = (const int*)d_in[2];   // [B] int32
  const float* W    = (const float*)d_in[3]; // [H,4H] f32
  const float* bias = (const float*)d_in[4]; // [H] f32

  float* out0   = (float*)d_out;                        // B*H f32
  float* attn_o = out0 + (size_t)BATCH * HID;           // B*S f32

  float* pacc = (float*)d_ws;                           // B*STRIPES*HID f32 (1 MB)
  float* pmd  = pacc + (size_t)BATCH * STRIPES * HID;   // B*STRIPES*2 f32

  k_pass1<<<BATCH * STRIPES, 256, 0, stream>>>(outp, ctx, spl, attn_o, pacc, pmd);
  k_final<<<BATCH * 8,        64, 0, stream>>>(outp, ctx, spl, W, bias, pacc, pmd, out0);
}

// Round 4
// 123.242 us; speedup vs baseline: 1.9575x; 1.1267x over previous
//
#include <hip/hip_runtime.h>
#include <math.h>

#define BATCH 32
#define SEQ   8192
#define HID   512
#define STRIPES 16                        // pass1 blocks per batch
#define RPB   (SEQ / STRIPES)             // 512 rows per block
#define CR    16                          // chunk rows (32 KB per chunk)
#define NCHUNK (RPB / CR)                 // 32 chunks

typedef float f4 __attribute__((ext_vector_type(4)));

#define VMWAIT(N) do { asm volatile("s_waitcnt vmcnt(" #N ")" ::: "memory"); \
                       __builtin_amdgcn_sched_barrier(0); } while (0)
#define LGKMWAIT0 do { asm volatile("s_waitcnt lgkmcnt(0)" ::: "memory"); \
                       __builtin_amdgcn_sched_barrier(0); } while (0)

__device__ __forceinline__ void gload_lds(const float* g, float* l) {
  __builtin_amdgcn_global_load_lds(
      (const __attribute__((address_space(1))) void*)g,
      (__attribute__((address_space(3))) void*)l, 16, 0, 0);
}

// Pass 1: fused attn-dot + raw-attn store + online masked softmax partials.
// Per-wave private pipeline: wave w stages ONLY rows 4w..4w+3 of each chunk
// (global_load_lds, 2 chunks in flight), so NO barriers in the main loop —
// just counted s_waitcnt vmcnt(N) per wave (T4).
__global__ __launch_bounds__(256, 2) void k_pass1(
    const float* __restrict__ outp, const float* __restrict__ ctx,
    const int* __restrict__ split, float* __restrict__ attn_out,
    float* __restrict__ pacc, float* __restrict__ pmd)
{
  __shared__ float lds[2][CR][HID];       // 2 x 32 KB
  const int tid = threadIdx.x, lane = tid & 63, wave = tid >> 6;
  const int b = blockIdx.x >> 4;          // STRIPES == 16
  const int stripe = blockIdx.x & 15;
  const int sp = split[b];
  const int s_base = stripe * RPB;

  const float* ob = outp + b * HID + lane * 8;
  const f4 o0 = *(const f4*)ob;
  const f4 o1 = *(const f4*)(ob + 4);

  const float* cbase = ctx + ((size_t)b * SEQ + s_base) * HID;
  float* ao = attn_out + (size_t)b * SEQ + s_base;

  // prologue: chunk0 -> buf0, chunk1 -> buf1 (own wave region: rows 4w..4w+3)
#pragma unroll
  for (int i = 0; i < 8; ++i) {
    const int o = (wave * 8 + i) * 256;
    gload_lds(cbase + o + lane * 4, &lds[0][0][0] + o);
  }
#pragma unroll
  for (int i = 0; i < 8; ++i) {
    const int o = (wave * 8 + i) * 256;
    gload_lds(cbase + CR * HID + o + lane * 4, &lds[1][0][0] + o);
  }

  float m = -INFINITY, d = 0.f;
  f4 acc0 = {0.f, 0.f, 0.f, 0.f}, acc1 = {0.f, 0.f, 0.f, 0.f};

#pragma unroll 1
  for (int c = 0; c < NCHUNK; ++c) {
    // wait for chunk c's 8 loads (oldest); robust to store/load order per iter
    if (c == 0)                 VMWAIT(8);
    else if (c == NCHUNK - 1)   VMWAIT(1);
    else                        VMWAIT(9);

    const int cur = c & 1;
    f4 c0[4], c1[4];
#pragma unroll
    for (int k = 0; k < 4; ++k) {
      const float* rp = &lds[cur][wave * 4 + k][lane * 8];
      c0[k] = *(const f4*)rp;
      c1[k] = *(const f4*)(rp + 4);
    }
    LGKMWAIT0;   // rows now in regs -> safe to overwrite buf[cur]

    if (c + 2 < NCHUNK) {       // prefetch chunk c+2 into buf[cur]
      const float* src = cbase + (size_t)(c + 2) * CR * HID;
      float* dst = &lds[cur][0][0];
#pragma unroll
      for (int i = 0; i < 8; ++i) {
        const int o = (wave * 8 + i) * 256;
        gload_lds(src + o + lane * 4, dst + o);
      }
    }

    float a4[4];
#pragma unroll
    for (int k = 0; k < 4; ++k) {
      float v = o0[0]*c0[k][0] + o0[1]*c0[k][1] + o0[2]*c0[k][2] + o0[3]*c0[k][3]
              + o1[0]*c1[k][0] + o1[1]*c1[k][1] + o1[2]*c1[k][2] + o1[3]*c1[k][3];
#pragma unroll
      for (int off = 32; off >= 1; off >>= 1) v += __shfl_xor(v, off, 64);
      a4[k] = v;
    }
    if (lane == 0) {
      f4 st = {a4[0], a4[1], a4[2], a4[3]};
      *(f4*)(ao + c * CR + wave * 4) = st;   // raw attn (1 vmem store/iter)
    }
#pragma unroll
    for (int k = 0; k < 4; ++k) {
      const int s = s_base + c * CR + wave * 4 + k;  // wave-uniform branch
      if (s < sp) {
        const float v  = a4[k];
        const float nm = fmaxf(m, v);
        const float sc = __expf(m - nm);
        const float w  = __expf(v - nm);
        d = d * sc + w;
        acc0 = acc0 * sc + w * c0[k];
        acc1 = acc1 * sc + w * c1[k];
        m = nm;
      }
    }
  }

  __syncthreads();                        // all waves done with buffers
  float* lacc = &lds[0][0][0];            // [4][HID]
  float* lmd  = &lds[1][0][0];            // [4][2]
  *(f4*)(lacc + wave * HID + lane * 8)     = acc0;
  *(f4*)(lacc + wave * HID + lane * 8 + 4) = acc1;
  if (lane == 0) { lmd[wave * 2] = m; lmd[wave * 2 + 1] = d; }
  __syncthreads();

  const float M = fmaxf(fmaxf(lmd[0], lmd[2]), fmaxf(lmd[4], lmd[6]));
  const size_t pb = (size_t)b * STRIPES + stripe;
  float* pa = pacc + pb * HID;
  if (M == -INFINITY) {
    pa[tid * 2] = 0.f; pa[tid * 2 + 1] = 0.f;
    if (tid == 0) { pmd[pb * 2] = -INFINITY; pmd[pb * 2 + 1] = 0.f; }
  } else {
    float e[4], Dl = 0.f;
#pragma unroll
    for (int wv = 0; wv < 4; ++wv) {
      const float mw = lmd[wv * 2];
      e[wv] = (mw == -INFINITY) ? 0.f : __expf(mw - M);
      Dl += e[wv] * lmd[wv * 2 + 1];
    }
    float s0 = 0.f, s1 = 0.f;
#pragma unroll
    for (int wv = 0; wv < 4; ++wv) {
      s0 += e[wv] * lacc[wv * HID + tid * 2];
      s1 += e[wv] * lacc[wv * HID + tid * 2 + 1];
    }
    pa[tid * 2] = s0; pa[tid * 2 + 1] = s1;
    if (tid == 0) { pmd[pb * 2] = M; pmd[pb * 2 + 1] = Dl; }
  }
}

// Pass 2: block (b,q) -> 64 outputs. 4-way k-split per h (tid = hl*4+part),
// parts: 0,1 -> amix halves of W row; 2 -> det; 3 -> output. LDS bank-padded.
__global__ __launch_bounds__(256) void k_final(
    const float* __restrict__ outp, const float* __restrict__ ctx,
    const int* __restrict__ split, const float* __restrict__ W,
    const float* __restrict__ bias, const float* __restrict__ pacc,
    const float* __restrict__ pmd, float* __restrict__ out0)
{
  const int b = blockIdx.x >> 3, q = blockIdx.x & 7;
  const int tid = threadIdx.x;
  __shared__ float comb[3 * HID + 8];
  float* amixp = comb;                 // [0, 512)
  float* detp  = comb + HID + 4;       // bank offset +4
  float* oupp  = comb + 2 * HID + 8;   // bank offset +8

  float M = -INFINITY;
#pragma unroll
  for (int c = 0; c < STRIPES; ++c) M = fmaxf(M, pmd[(b * STRIPES + c) * 2]);
  float wgt[STRIPES], D = 0.f;
#pragma unroll
  for (int c = 0; c < STRIPES; ++c) {
    const float mw = pmd[(b * STRIPES + c) * 2];
    wgt[c] = (mw == -INFINITY) ? 0.f : __expf(mw - M);
    D += wgt[c] * pmd[(b * STRIPES + c) * 2 + 1];
  }
  const float invD = 1.f / D;
  const int sp = split[b];
#pragma unroll
  for (int col = tid; col < HID; col += 256) {
    float s = 0.f;
#pragma unroll
    for (int c = 0; c < STRIPES; ++c)
      s += wgt[c] * pacc[((size_t)(b * STRIPES + c)) * HID + col];
    amixp[col] = s * invD;
    detp[col]  = ctx[((size_t)b * SEQ + sp) * HID + col];
    oupp[col]  = outp[b * HID + col];
  }
  __syncthreads();

  const int hl = tid >> 2, part = tid & 3;
  const int h = q * 64 + hl;
  const float* wr = W + (size_t)h * (4 * HID) + part * HID;
  const float* src = (part == 2) ? detp : (part == 3 ? oupp : amixp);
  float acc = 0.f;
#pragma unroll 4
  for (int k0 = 0; k0 < HID; k0 += 4) {
    const f4 w = *(const f4*)(wr + k0);
    const f4 x = *(const f4*)(src + k0);
    acc += w[0]*x[0] + w[1]*x[1] + w[2]*x[2] + w[3]*x[3];
  }
  acc += __shfl_xor(acc, 1, 64);
  acc += __shfl_xor(acc, 2, 64);
  if (part == 0) out0[b * HID + h] = tanhf(acc + bias[h]);
}

extern "C" void kernel_launch(void* const* d_in, const int* in_sizes, int n_in,
                              void* d_out, int out_size, void* d_ws, size_t ws_size,
                              hipStream_t stream)
{
  const float* outp = (const float*)d_in[0]; // [B,1,H] f32
  const float* ctx  = (const float*)d_in[1]; // [B,S,H] f32
  const int*   spl  = (const int*)d_in[2];   // [B] int32
  const float* W    = (const float*)d_in[3]; // [H,4H] f32
  const float* bias = (const float*)d_in[4]; // [H] f32

  float* out0   = (float*)d_out;                        // B*H f32
  float* attn_o = out0 + (size_t)BATCH * HID;           // B*S f32

  float* pacc = (float*)d_ws;                           // B*STRIPES*HID f32 (1 MB)
  float* pmd  = pacc + (size_t)BATCH * STRIPES * HID;   // B*STRIPES*2 f32

  k_pass1<<<BATCH * STRIPES, 256, 0, stream>>>(outp, ctx, spl, attn_o, pacc, pmd);
  k_final<<<BATCH * 8,       256, 0, stream>>>(outp, ctx, spl, W, bias, pacc, pmd, out0);
}